// Round 1
// 1028.837 us; speedup vs baseline: 1.0452x; 1.0452x over previous
//
#include <hip/hip_runtime.h>
#include <hip/hip_bf16.h>
#include <stdint.h>

// LSTM cell, B=8192, IN=H=2048. Fused GEMM: M=8192, N=8192 (4 gates x 2048), K=4096.
// fp32 I/O, bf16 MFMA compute. Round 4: conflict-free chunk-major LDS layout.
// Round 3 was LDS-bank-conflict bound (1.5e8 conflict cycles, ~8-way on ds_read_b128
// from 64B-row tiles). Abf/Wt are now stored pre-tiled in (K-step, kc, row) order =
// exact LDS order, so global_load_lds stays linear (rule #21) AND every fragment
// ds_read_b128 is lane-consecutive 16B (0 conflicts). Also: 2-phase LDS double-buffer
// (one barrier per K-step, prefetch flies under MFMA).

typedef short bf16x8 __attribute__((ext_vector_type(8)));
typedef float f32x4 __attribute__((ext_vector_type(4)));
typedef float f32x16 __attribute__((ext_vector_type(16)));

typedef const __attribute__((address_space(1))) void* gptr_as1;
typedef __attribute__((address_space(3))) void* lptr_as3;

__device__ __forceinline__ void g2lds16(const void* g, void* l) {
  __builtin_amdgcn_global_load_lds((gptr_as1)g, (lptr_as3)l, 16, 0, 0);
}

__device__ __forceinline__ short f2bs(float x) {
  __hip_bfloat16 h = __float2bfloat16(x);  // RNE
  return *reinterpret_cast<short*>(&h);
}

// ---------------------------------------------------------------------------
// Tiled Wt layout (fast path). Chunk = 8 bf16 along K.
//   W_off(jb, s, kc, r) = (((jb*128 + s)*4 + kc)*128 + r) * 8 elems
//   jb = j-block (32 cols/gate) 0..63, s = K-step (32) 0..127, kc = K-chunk 0..3,
//   r = g*32 + jj (gate-major gathered column) 0..127.
// One (jb,s) tile = 512 chunks = 8 KB = exactly the main kernel's B LDS buffer.
// ---------------------------------------------------------------------------
__global__ __launch_bounds__(256) void transpose_w_tiled(
    const float* __restrict__ Wi, const float* __restrict__ Wh,
    __hip_bfloat16* __restrict__ Wt) {
  __shared__ float tile[64][65];
  const int nt = blockIdx.x * 64;   // 128 blocks (within one gate: 2048%64==0)
  const int kt = blockIdx.y * 64;   // 64 blocks
  const float* src = (kt < 2048) ? (Wi + (size_t)kt * 8192)
                                 : (Wh + (size_t)(kt - 2048) * 8192);
  const int t = threadIdx.x;
#pragma unroll
  for (int i = 0; i < 4; ++i) {
    const int c = i * 256 + t;            // 0..1023
    const int kr = c >> 4, cc = c & 15;
    const float4 v = *(const float4*)(src + (size_t)kr * 8192 + nt + cc * 4);
    tile[kr][cc * 4 + 0] = v.x;
    tile[kr][cc * 4 + 1] = v.y;
    tile[kr][cc * 4 + 2] = v.z;
    tile[kr][cc * 4 + 3] = v.w;
  }
  __syncthreads();
  const int g  = nt >> 11;        // gate (uniform per block)
  const int nb = nt & 2047;       // col base within gate
#pragma unroll
  for (int i = 0; i < 2; ++i) {
    const int c = i * 256 + t;            // 0..511
    const int ck = c >> 6, nr = c & 63;   // nr fastest: conflict-free LDS col read,
                                          // writes contiguous in r per 32-lane group
    bf16x8 o;
#pragma unroll
    for (int j = 0; j < 8; ++j) o[j] = f2bs(tile[ck * 8 + j][nr]);
    const int nl = nb + nr;
    const int jb = nl >> 5, jj = nl & 31;
    const int s  = (kt >> 5) + (ck >> 2);
    const int kc = ck & 3;
    const int r  = g * 32 + jj;
    *(bf16x8*)(Wt + (((size_t)(jb * 128 + s) * 4 + kc) * 128 + r) * 8) = o;
  }
}

// ---------------------------------------------------------------------------
// Tiled Abf layout (fast path).
//   A_off(p, s, kc, m) = (((p*128 + s)*4 + kc)*256 + m) * 8 elems
//   p = M-panel (256 rows) 0..31, s = K-step 0..127, kc 0..3, m = local row 0..255.
// One (p,s) tile = 1024 chunks = 16 KB = exactly the main kernel's A LDS buffer.
// k < 2048 from X, else Hp (s < 64 <=> k < 2048 since s-tiles don't straddle).
// Thread = one (row, s): reads 128 B contiguous (8x float4, L1-resident after #0),
// writes 4 chunks, each lane-consecutive across the wave (1 KB segments).
// ---------------------------------------------------------------------------
__global__ __launch_bounds__(256) void convert_a(const float* __restrict__ X,
                                                 const float* __restrict__ Hp,
                                                 __hip_bfloat16* __restrict__ Abf) {
  const int b = blockIdx.x;             // 4096
  const int p = b >> 7, s = b & 127;
  const int t = threadIdx.x;
  const int m = p * 256 + t;
  const float* src = (s < 64) ? (X + (size_t)m * 2048 + s * 32)
                              : (Hp + (size_t)m * 2048 + (s - 64) * 32);
  float v[32];
#pragma unroll
  for (int i = 0; i < 8; ++i) {
    const float4 f = *(const float4*)(src + i * 4);
    v[i * 4 + 0] = f.x; v[i * 4 + 1] = f.y;
    v[i * 4 + 2] = f.z; v[i * 4 + 3] = f.w;
  }
  __hip_bfloat16* dst = Abf + ((size_t)(p * 128 + s) * 1024) * 8 + t * 8;
#pragma unroll
  for (int kc = 0; kc < 4; ++kc) {
    bf16x8 o;
#pragma unroll
    for (int j = 0; j < 8; ++j) o[j] = f2bs(v[kc * 8 + j]);
    *(bf16x8*)(dst + kc * 2048) = o;
  }
}

// ---------------------------------------------------------------------------
// Fast path: block tile 256(M) x 128(gathered N = 4 gates x 32 j), BK=32.
// 4 waves stacked in M; wave = 64 rows x 4 gate-tiles x 2 m-tiles of 32x32x16 MFMA.
// A/B operand: X[m=lane&31][k=(lane>>5)*8+j]; C/D (m74/m101): col=lane&31,
// row=(reg&3)+8*(reg>>2)+4*(lane>>5).
// LDS chunk-major [kc][row][8]: fragment reads are lane-consecutive 16B => 0 bank
// conflicts; staging is 6 fully-contiguous global_load_lds_dwordx4 per thread.
// 2-phase double-buffer: stage(s+1) || compute(s); one __syncthreads per K-step
// (its vmcnt(0)+lgkmcnt(0) drain is both the "next tile ready" and the
// "reads done before overwrite" fence).
// ---------------------------------------------------------------------------
__global__ __launch_bounds__(256, 2) void lstm_fused(
    const __hip_bfloat16* __restrict__ Abf,   // tiled, see A_off
    const __hip_bfloat16* __restrict__ Wt,    // tiled, see W_off
    const float* __restrict__ Cp,             // [8192][2048]
    const float* __restrict__ bi,             // [8192]
    const float* __restrict__ bh,             // [8192]
    float* __restrict__ out)                  // [3][8192][2048]
{
  __shared__ __align__(16) __hip_bfloat16 As[2][8192];  // [buf][kc*256 + m][8]
  __shared__ __align__(16) __hip_bfloat16 Bs[2][4096];  // [buf][kc*128 + r][8]
  const int t   = threadIdx.x;
  const int p   = blockIdx.x;      // M panel (32)
  const int jbl = blockIdx.y;      // j block (64)
  const int m0 = p * 256, j0 = jbl * 32;

  const __hip_bfloat16* Ab = Abf + (size_t)p   * (128 * 8192);
  const __hip_bfloat16* Bb = Wt  + (size_t)jbl * (128 * 4096);

  const int w = t >> 6, lane = t & 63;
  const int lm = lane & 31, lk = lane >> 5;

  f32x16 acc[2][4];
#pragma unroll
  for (int a = 0; a < 2; ++a)
#pragma unroll
    for (int b = 0; b < 4; ++b)
#pragma unroll
      for (int r = 0; r < 16; ++r) acc[a][b][r] = 0.f;

  auto stage = [&](int buf, int s) {
    const __hip_bfloat16* as = Ab + (size_t)s * 8192 + t * 8;
    __hip_bfloat16* la = &As[buf][t * 8];
#pragma unroll
    for (int i = 0; i < 4; ++i) g2lds16(as + i * 2048, la + i * 2048);
    const __hip_bfloat16* bs = Bb + (size_t)s * 4096 + t * 8;
    __hip_bfloat16* lb = &Bs[buf][t * 8];
#pragma unroll
    for (int i = 0; i < 2; ++i) g2lds16(bs + i * 2048, lb + i * 2048);
  };

  stage(0, 0);
  __syncthreads();                 // drains vmcnt(0): buf0 ready
  int cur = 0;
  for (int s = 0; s < 128; ++s) {
    if (s < 127) stage(cur ^ 1, s + 1);   // prefetch flies under MFMA
#pragma unroll
    for (int kk = 0; kk < 2; ++kk) {
      const int kcA = (2 * kk + lk) * 256;
      const int kcB = (2 * kk + lk) * 128;
      bf16x8 af[2], bv[4];
#pragma unroll
      for (int tm = 0; tm < 2; ++tm)
        af[tm] = *(const bf16x8*)(&As[cur][(kcA + w * 64 + tm * 32 + lm) * 8]);
#pragma unroll
      for (int g = 0; g < 4; ++g)
        bv[g] = *(const bf16x8*)(&Bs[cur][(kcB + g * 32 + lm) * 8]);
#pragma unroll
      for (int tm = 0; tm < 2; ++tm)
#pragma unroll
        for (int g = 0; g < 4; ++g)
          acc[tm][g] = __builtin_amdgcn_mfma_f32_32x32x16_bf16(af[tm], bv[g],
                                                               acc[tm][g], 0, 0, 0);
    }
    __syncthreads();               // next tile ready AND reads done before overwrite
    cur ^= 1;
  }

  const int j = j0 + lm;
  float bsum[4];
#pragma unroll
  for (int g = 0; g < 4; ++g) bsum[g] = bi[g * 2048 + j] + bh[g * 2048 + j];

#pragma unroll
  for (int tm = 0; tm < 2; ++tm) {
#pragma unroll
    for (int r = 0; r < 16; ++r) {
      const int rowcd = (r & 3) + 8 * (r >> 2) + 4 * lk;
      const int m = m0 + w * 64 + tm * 32 + rowcd;
      const size_t off = (size_t)m * 2048 + j;
      const float fp = acc[tm][0][r] + bsum[0];
      const float ip = acc[tm][1][r] + bsum[1];
      const float gp = acc[tm][2][r] + bsum[2];
      const float op = acc[tm][3][r] + bsum[3];
      const float ft = 1.f / (1.f + __expf(-fp));
      const float it = 1.f / (1.f + __expf(-ip));
      const float gt = 1.f - 2.f / (1.f + __expf(2.f * gp));
      const float ot = 1.f / (1.f + __expf(-op));
      const float ct = ft * Cp[off] + it * gt;
      const float ht = ot * (1.f - 2.f / (1.f + __expf(2.f * ct)));
      out[off] = ht;
      out[16777216 + off] = ht;
      out[33554432 + off] = ct;
    }
  }
}

// ---------------------------------------------------------------------------
// Fallback path (ws too small for Abf): original row-major Wt[n][k] transpose +
// round-2 kernel, fp32 A staged to LDS. PASSED previously; unchanged.
// ---------------------------------------------------------------------------
__global__ __launch_bounds__(256) void transpose_w_nk(const float* __restrict__ Wi,
                                                      const float* __restrict__ Wh,
                                                      __hip_bfloat16* __restrict__ Wt) {
  __shared__ float tile[64][65];
  const int nt = blockIdx.x * 64;
  const int kt = blockIdx.y * 64;
  const float* src = (kt < 2048) ? (Wi + (size_t)kt * 8192)
                                 : (Wh + (size_t)(kt - 2048) * 8192);
  const int t = threadIdx.x;
#pragma unroll
  for (int i = 0; i < 4; ++i) {
    const int c = i * 256 + t;
    const int kr = c >> 4, cc = c & 15;
    const float4 v = *(const float4*)(src + (size_t)kr * 8192 + nt + cc * 4);
    tile[kr][cc * 4 + 0] = v.x;
    tile[kr][cc * 4 + 1] = v.y;
    tile[kr][cc * 4 + 2] = v.z;
    tile[kr][cc * 4 + 3] = v.w;
  }
  __syncthreads();
#pragma unroll
  for (int i = 0; i < 2; ++i) {
    const int c = i * 256 + t;
    const int nr = c >> 3, ck = c & 7;
    bf16x8 o;
#pragma unroll
    for (int j = 0; j < 8; ++j) o[j] = f2bs(tile[ck * 8 + j][nr]);
    *(bf16x8*)(Wt + (size_t)(nt + nr) * 4096 + kt + ck * 8) = o;
  }
}

__global__ __launch_bounds__(256) void lstm_fused_f32a(
    const float* __restrict__ X, const float* __restrict__ Hp,
    const float* __restrict__ Cp, const __hip_bfloat16* __restrict__ Wt,
    const float* __restrict__ bi, const float* __restrict__ bh,
    float* __restrict__ out)
{
  __shared__ __align__(16) float As[4096];
  __shared__ __align__(16) __hip_bfloat16 Bs[4096];
  const int t  = threadIdx.x;
  const int m0 = blockIdx.x * 128;
  const int j0 = blockIdx.y * 32;

  const float* gax[4]; const float* gah[4]; float* la[4];
#pragma unroll
  for (int i = 0; i < 4; ++i) {
    const int c = i * 256 + t;
    const int row = c >> 3, pos = c & 7;
    const int qg = pos ^ (row & 7);
    gax[i] = X  + (size_t)(m0 + row) * 2048 + qg * 4;
    gah[i] = Hp + (size_t)(m0 + row) * 2048 + qg * 4;
    la[i]  = As + c * 4;
  }
  const __hip_bfloat16* gb[2]; __hip_bfloat16* lb[2];
#pragma unroll
  for (int i = 0; i < 2; ++i) {
    const int c = i * 256 + t;
    const int row = c >> 2, pos = c & 3;
    const int qg = pos ^ ((row >> 1) & 3);
    const int n = (row >> 5) * 2048 + j0 + (row & 31);
    gb[i] = Wt + (size_t)n * 4096 + qg * 8;
    lb[i] = Bs + c * 8;
  }

  const int w = t >> 6, lane = t & 63;
  const int wr = w >> 1, wc = w & 1;
  const int lq = lane >> 4, ln = lane & 15;

  f32x4 acc[4][4];
#pragma unroll
  for (int a = 0; a < 4; ++a)
#pragma unroll
    for (int b = 0; b < 4; ++b) acc[a][b] = (f32x4){0.f, 0.f, 0.f, 0.f};

  for (int k0 = 0; k0 < 4096; k0 += 32) {
    __syncthreads();
    if (k0 < 2048) {
#pragma unroll
      for (int i = 0; i < 4; ++i) g2lds16(gax[i] + k0, la[i]);
    } else {
#pragma unroll
      for (int i = 0; i < 4; ++i) g2lds16(gah[i] + (k0 - 2048), la[i]);
    }
#pragma unroll
    for (int i = 0; i < 2; ++i) g2lds16(gb[i] + k0, lb[i]);
    __syncthreads();

    bf16x8 af[4], bv[4];
#pragma unroll
    for (int tm = 0; tm < 4; ++tm) {
      const int m = wr * 64 + tm * 16 + ln;
      const f32x4 f0 = *(const f32x4*)(As + m * 32 + ((lq * 2)     ^ (m & 7)) * 4);
      const f32x4 f1 = *(const f32x4*)(As + m * 32 + ((lq * 2 + 1) ^ (m & 7)) * 4);
      bf16x8 v;
      v[0] = f2bs(f0[0]); v[1] = f2bs(f0[1]); v[2] = f2bs(f0[2]); v[3] = f2bs(f0[3]);
      v[4] = f2bs(f1[0]); v[5] = f2bs(f1[1]); v[6] = f2bs(f1[2]); v[7] = f2bs(f1[3]);
      af[tm] = v;
    }
#pragma unroll
    for (int g = 0; g < 4; ++g) {
      const int row = g * 32 + wc * 16 + ln;
      bv[g] = *(const bf16x8*)(Bs + row * 32 + (lq ^ ((row >> 1) & 3)) * 8);
    }
#pragma unroll
    for (int tm = 0; tm < 4; ++tm)
#pragma unroll
      for (int g = 0; g < 4; ++g)
        acc[tm][g] = __builtin_amdgcn_mfma_f32_16x16x32_bf16(af[tm], bv[g],
                                                             acc[tm][g], 0, 0, 0);
  }

  const int jg = j0 + wc * 16 + ln;
  float bsum[4];
#pragma unroll
  for (int g = 0; g < 4; ++g) bsum[g] = bi[g * 2048 + jg] + bh[g * 2048 + jg];

#pragma unroll
  for (int tm = 0; tm < 4; ++tm) {
#pragma unroll
    for (int r = 0; r < 4; ++r) {
      const int m = m0 + wr * 64 + tm * 16 + lq * 4 + r;
      const size_t off = (size_t)m * 2048 + jg;
      const float fp = acc[tm][0][r] + bsum[0];
      const float ip = acc[tm][1][r] + bsum[1];
      const float gp = acc[tm][2][r] + bsum[2];
      const float op = acc[tm][3][r] + bsum[3];
      const float ft = 1.f / (1.f + __expf(-fp));
      const float it = 1.f / (1.f + __expf(-ip));
      const float gt = 1.f - 2.f / (1.f + __expf(2.f * gp));
      const float ot = 1.f / (1.f + __expf(-op));
      const float ct = ft * Cp[off] + it * gt;
      const float ht = ot * (1.f - 2.f / (1.f + __expf(2.f * ct)));
      out[off] = ht;
      out[16777216 + off] = ht;
      out[33554432 + off] = ct;
    }
  }
}

extern "C" void kernel_launch(void* const* d_in, const int* in_sizes, int n_in,
                              void* d_out, int out_size, void* d_ws, size_t ws_size,
                              hipStream_t stream) {
  const float* X  = (const float*)d_in[0];
  const float* Hp = (const float*)d_in[1];
  const float* Cp = (const float*)d_in[2];
  const float* Wi = (const float*)d_in[3];
  const float* bi = (const float*)d_in[4];
  const float* Wh = (const float*)d_in[5];
  const float* bh = (const float*)d_in[6];
  float* out = (float*)d_out;
  __hip_bfloat16* Wt = (__hip_bfloat16*)d_ws;          // 64 MB

  if (ws_size >= (size_t)134217728) {                  // 128 MB: Wt + Abf (tiled)
    __hip_bfloat16* Abf = (__hip_bfloat16*)d_ws + 33554432;
    transpose_w_tiled<<<dim3(128, 64), dim3(256), 0, stream>>>(Wi, Wh, Wt);
    convert_a<<<4096, 256, 0, stream>>>(X, Hp, Abf);
    lstm_fused<<<dim3(32, 64), 256, 0, stream>>>(Abf, Wt, Cp, bi, bh, out);
  } else {
    transpose_w_nk<<<dim3(128, 64), dim3(256), 0, stream>>>(Wi, Wh, Wt);
    lstm_fused_f32a<<<dim3(64, 64), 256, 0, stream>>>(X, Hp, Cp, Wt, bi, bh, out);
  }
}